// Round 8
// baseline (120.588 us; speedup 1.0000x reference)
//
#include <hip/hip_runtime.h>

// IndexedLinear: out[z, s*V:(s+1)*V] = coeff[s] * x[z, s*U:(s+1)*U] @ W[seg(z), s]
// S=8, U=V=32, C=32, Z=65536.
//
// R13: R8 + LDS-transpose epilogue -> CONTIGUOUS streaming stores.
// Evidence: R5..R12 (6 disjoint schedules) all 117.9-122.6us => scheduling/
// latency/occupancy theories dead. R10 decomposition: pass2 (warm) = 16us
// with a pure-HBM-write phase of 66 MiB => 4.1 TB/s nt-write rate, 35% below
// the fill's 6.3 TB/s. The never-varied invariant is the STORE SHAPE: every
// round wrote per-wave 128B chunks at 1KB stride (column-slice of the output
// row) as 32 scalar dword nt stores -> channel-imbalanced bursts.
// Fix: block output (rows z0..z0+31 x 1KB) is one contiguous 32KB span.
// Waves write acc into a 32KB LDS tile (32 lanes -> 32 banks, 2 lanes/bank =
// free), one barrier, then a LINEAR 32KB LDS->global copy: 8x ds_read_b128 +
// 8x contiguous dwordx4 nt stores per thread (1KB/instr, sequential 8KB runs,
// channel-uniform, 4x fewer store instrs).
// Everything else is R8 verbatim: zero-LDS-staging direct coalesced A loads,
// B frags (coeff folded, packed cvt), verified C/D map (now into LDS), fp32
// boundary fallback (direct stores, no barrier -- uni is block-uniform).

constexpr int S = 8, U = 32, V = 32, C = 32, Z = 65536;
constexpr int SU = S * U;   // 256 floats per X row
constexpr int SV = S * V;   // 256 floats per out row
constexpr int NT = 256;     // 4 waves; wave w owns s in {2w, 2w+1}
constexpr int BZ = 32;      // z rows per block

typedef float    f4     __attribute__((ext_vector_type(4)));
typedef float    f32x16 __attribute__((ext_vector_type(16)));
typedef short    bf16x8 __attribute__((ext_vector_type(8)));
typedef unsigned u32x4  __attribute__((ext_vector_type(4)));

// packed RNE f32x2 -> bf16x2 (bit-identical to verified manual f2bf)
__device__ __forceinline__ unsigned cvtpk(float lo, float hi) {
  unsigned r;
  asm("v_cvt_pk_bf16_f32 %0, %1, %2" : "=v"(r) : "v"(lo), "v"(hi));
  return r;
}

__global__ __launch_bounds__(NT) void IndexedLinear_kernel(
    const float* __restrict__ W_all,   // (C, S*U*V)
    const float* __restrict__ X,       // (Z, S*U)
    const int*   __restrict__ counts,  // (C,)
    const float* __restrict__ coeff,   // (S,)
    float*       __restrict__ out)     // (Z, S*V)
{
  const int tid  = threadIdx.x;
  const int lane = tid & 63;
  const int w    = tid >> 6;
  const int z0   = blockIdx.x * BZ;

  const int m  = lane & 31;   // A row / B col / C col
  const int h  = lane >> 5;   // k-half
  const int s0 = 2 * w;

  // block output staging tile: [32 rows][256 cols] fp32 = 32 KiB
  __shared__ float OL[BZ * SV];

  // ---- segment exclusive-prefix scan (per wave) ----
  int cnt = (lane < C) ? counts[lane] : 0;
  int inc = cnt;
  #pragma unroll
  for (int d = 1; d < 32; d <<= 1) {
    int o = __shfl_up(inc, d, 64);
    if (lane >= d) inc += o;
  }
  const int exc = inc - cnt;
  const unsigned long long ma = __ballot(lane < C && exc <= z0);
  const unsigned long long mb = __ballot(lane < C && exc <= z0 + BZ - 1);
  const int segA = __popcll(ma) - 1;
  const int segB = __popcll(mb) - 1;
  const bool uni = (segA == segB);   // identical across the block's waves

  if (uni) {
    // ---- A: direct global loads, lane (m,h) reads its contiguous 32B row
    //      slices for both s-tiles (8x global_load_dwordx4) ----
    const f4* Xr = (const f4*)X + (size_t)(z0 + m) * (SU / 4) + 2 * h;
    f4 xs[8];
    #pragma unroll
    for (int tt = 0; tt < 2; ++tt) {
      const int c0 = (s0 + tt) * 8;
      xs[4 * tt + 0] = Xr[c0 + 0];
      xs[4 * tt + 1] = Xr[c0 + 1];
      xs[4 * tt + 2] = Xr[c0 + 4];
      xs[4 * tt + 3] = Xr[c0 + 5];
    }

    // ---- B fragments (L2-hot W, coeff folded), packed converts ----
    const float* wseg = W_all + (size_t)segA * (S * U * V);
    u32x4 b1[2], b2[2];
    #pragma unroll
    for (int tt = 0; tt < 2; ++tt) {
      const int s = s0 + tt;
      const float cs = coeff[s];
      const float* wb = wseg + s * (U * V) + m;
      #pragma unroll
      for (int j = 0; j < 4; ++j) {
        b1[tt][j] = cvtpk(wb[(8 * h + 2 * j) * V] * cs,
                          wb[(8 * h + 2 * j + 1) * V] * cs);
        b2[tt][j] = cvtpk(wb[(16 + 8 * h + 2 * j) * V] * cs,
                          wb[(16 + 8 * h + 2 * j + 1) * V] * cs);
      }
    }

    #pragma unroll
    for (int tt = 0; tt < 2; ++tt) {
      const int s = s0 + tt;
      const f4 xa = xs[4 * tt + 0], xb = xs[4 * tt + 1];
      const f4 xc = xs[4 * tt + 2], xd = xs[4 * tt + 3];
      u32x4 pa, pb;
      pa[0] = cvtpk(xa[0], xa[1]); pa[1] = cvtpk(xa[2], xa[3]);
      pa[2] = cvtpk(xb[0], xb[1]); pa[3] = cvtpk(xb[2], xb[3]);
      pb[0] = cvtpk(xc[0], xc[1]); pb[1] = cvtpk(xc[2], xc[3]);
      pb[2] = cvtpk(xd[0], xd[1]); pb[3] = cvtpk(xd[2], xd[3]);
      const bf16x8 a1 = __builtin_bit_cast(bf16x8, pa);
      const bf16x8 a2 = __builtin_bit_cast(bf16x8, pb);
      f32x16 acc = {};
      acc = __builtin_amdgcn_mfma_f32_32x32x16_bf16(
          a1, __builtin_bit_cast(bf16x8, b1[tt]), acc, 0, 0, 0);
      acc = __builtin_amdgcn_mfma_f32_32x32x16_bf16(
          a2, __builtin_bit_cast(bf16x8, b2[tt]), acc, 0, 0, 0);

      // verified C/D map: reg r -> row (r&3)+8*(r>>2)+4h, col m.
      // write into LDS tile instead of global (32 lanes -> 32 banks;
      // h=0/h=1 pairs hit same bank at distinct addrs = free 2-way).
      float* lw = OL + s * V + m;
      #pragma unroll
      for (int r = 0; r < 16; ++r) {
        const int row = (r & 3) + 8 * (r >> 2) + 4 * h;
        lw[row * SV] = acc[r];
      }
    }

    __syncthreads();  // LDS tile complete (uni is block-uniform -> safe)

    // ---- epilogue: linear 32KB LDS -> global copy. thread tid, sweep j:
    //      f4 index j*256 + tid covers rows z0..z0+31 contiguously.
    //      per-instr: 64 lanes x 16B = 1KB contiguous; per-wave 8KB runs. ----
    const f4* lv = (const f4*)OL;
    f4* og = (f4*)(out + (size_t)z0 * SV);
    #pragma unroll
    for (int j = 0; j < 8; ++j) {
      const int idx = j * 256 + tid;
      __builtin_nontemporal_store(lv[idx], og + idx);
    }
  } else {
    // ---- fallback: block crosses a segment boundary (fp32 exact),
    //      direct stores, no barrier (all waves take this path together) ----
    const int zz = z0 + m;
    int sg = 0;
    #pragma unroll 1
    for (int i = 1; i < C; ++i) {
      const int pi = __shfl(exc, i, 64);
      if (pi <= zz) sg = i;
    }
    #pragma unroll 1
    for (int tt = 0; tt < 2; ++tt) {
      const int s = s0 + tt;
      const float cs = coeff[s];
      const float* wr = W_all + (size_t)sg * (S * U * V) + s * (U * V) + 16 * h;
      float accv[16] = {};
      #pragma unroll 1
      for (int cq = 0; cq < 8; ++cq) {
        const f4 xv = ((const f4*)X)[(size_t)zz * (SU / 4) + s * 8 + cq];
        #pragma unroll
        for (int ii = 0; ii < 4; ++ii) {
          const int u = cq * 4 + ii;
          const float xu = xv[ii];
          #pragma unroll
          for (int j = 0; j < 16; ++j) accv[j] += xu * wr[u * V + j];
        }
      }
      float* ob = out + (size_t)zz * SV + s * V + 16 * h;
      #pragma unroll
      for (int j = 0; j < 16; ++j) ob[j] = accv[j] * cs;
    }
  }
}

extern "C" void kernel_launch(void* const* d_in, const int* in_sizes, int n_in,
                              void* d_out, int out_size, void* d_ws, size_t ws_size,
                              hipStream_t stream) {
  const float* input1       = (const float*)d_in[0];  // (C, S*U*V)
  const float* input2       = (const float*)d_in[1];  // (Z, S*U)
  const int*   counts       = (const int*)d_in[2];    // (C,)
  const float* coefficients = (const float*)d_in[3];  // (S,)
  float*       out          = (float*)d_out;          // (Z, S*V)

  const int grid = Z / BZ;  // 2048 blocks, 4 waves each, 32KB LDS epilogue
  IndexedLinear_kernel<<<grid, NT, 0, stream>>>(input1, input2, counts,
                                                coefficients, out);
}